// Round 1
// baseline (907.355 us; speedup 1.0000x reference)
//
#include <hip/hip_runtime.h>

#define D 128

// ---------------------------------------------------------------------------
// Build transposed+concatenated weights for one layer:
//   WT[k*128 + d] = (k < 128) ? Wl[d*128 + k] : Wr[d*128 + (k-128)]
// so that out[t][d] = sum_k A[t][k] * WT[k][d] with A = [mean | x_self].
// All 3 layers in one launch: blocks 0-127 -> layer0, 128-255 -> layer1, ...
// ---------------------------------------------------------------------------
__global__ void build_wt_all(const float* __restrict__ Wl0, const float* __restrict__ Wr0,
                             const float* __restrict__ Wl1, const float* __restrict__ Wr1,
                             const float* __restrict__ Wl2, const float* __restrict__ Wr2,
                             float* __restrict__ WT /* [3][256][128] */) {
    const int layer = blockIdx.x >> 7;
    const int i = (blockIdx.x & 127) * 256 + threadIdx.x;   // [0, 32768)
    const float* Wl = (layer == 0) ? Wl0 : (layer == 1) ? Wl1 : Wl2;
    const float* Wr = (layer == 0) ? Wr0 : (layer == 1) ? Wr1 : Wr2;
    const int k = i >> 7;        // 0..255
    const int d = i & 127;       // 0..127
    const float v = (k < D) ? Wl[d * D + k] : Wr[d * D + (k - D)];
    WT[layer * 2 * D * D + i] = v;
}

// ---------------------------------------------------------------------------
// Fused SAGE layer: for M=32 targets per block,
//   Phase 1: mean over F gathered neighbor rows + self row -> LDS A[32][256]
//   Phase 2: out[t][:] = A[t][:] @ WT  (register-tiled matvec, optional ReLU)
// Nt is an exact multiple of 32 for all three layers.
// ---------------------------------------------------------------------------
template <int F>
__global__ __launch_bounds__(256, 4) void sage_layer(
        const float* __restrict__ x,    // [Ns, 128] source features
        const int*   __restrict__ src,  // [Nt * F]
        const float* __restrict__ WT,   // [256, 128]
        float*       __restrict__ out,  // [Nt, 128]
        int doRelu) {
    constexpr int M = 32;               // targets per block
    __shared__ float A[M][2 * D];       // 32 KB: [mean | x_self]

    const int tid  = threadIdx.x;
    const int lane = tid & 63;
    const int wave = tid >> 6;
    const int t0   = blockIdx.x * M;

    // ---- Phase 1: gather + mean (float2/lane => one full 512B row per instr)
    const float2* __restrict__ x2 = (const float2*)x;
    const float inv = 1.0f / (float)F;
    for (int mi = wave; mi < M; mi += 4) {
        const int t = t0 + mi;
        const int base = t * F;
        float2 acc = make_float2(0.f, 0.f);
#pragma unroll
        for (int j = 0; j < F; ++j) {
            const int s = src[base + j];                    // wave-uniform
            const float2 v = x2[(size_t)s * 64 + lane];     // coalesced 512B
            acc.x += v.x;
            acc.y += v.y;
        }
        const float2 xt = x2[(size_t)t * 64 + lane];        // self row
        A[mi][2 * lane]         = acc.x * inv;
        A[mi][2 * lane + 1]     = acc.y * inv;
        A[mi][D + 2 * lane]     = xt.x;
        A[mi][D + 2 * lane + 1] = xt.y;
    }
    __syncthreads();

    // ---- Phase 2: out[m][d] = sum_k A[m][k] * WT[k][d]
    // thread -> column d, row-parity r; 16 rows per thread.
    const int d = tid & (D - 1);
    const int r = tid >> 7;             // 0 or 1
    float acc[M / 2];
#pragma unroll
    for (int m = 0; m < M / 2; ++m) acc[m] = 0.f;

#pragma unroll 2
    for (int k = 0; k < 2 * D; k += 4) {
        const float w0 = WT[(k + 0) * D + d];   // coalesced, L2-resident
        const float w1 = WT[(k + 1) * D + d];
        const float w2 = WT[(k + 2) * D + d];
        const float w3 = WT[(k + 3) * D + d];
#pragma unroll
        for (int m = 0; m < M / 2; ++m) {
            const float4 a = *(const float4*)&A[2 * m + r][k];  // broadcast b128
            acc[m] = fmaf(a.x, w0, acc[m]);
            acc[m] = fmaf(a.y, w1, acc[m]);
            acc[m] = fmaf(a.z, w2, acc[m]);
            acc[m] = fmaf(a.w, w3, acc[m]);
        }
    }

#pragma unroll
    for (int m = 0; m < M / 2; ++m) {
        const int row = t0 + 2 * m + r;
        float v = acc[m];
        if (doRelu) v = fmaxf(v, 0.f);
        out[(size_t)row * D + d] = v;   // coalesced 512B stores
    }
}

// ---------------------------------------------------------------------------
// In-place log_softmax over rows of [Nrows, 128]; one wave per row.
// ---------------------------------------------------------------------------
__global__ void log_softmax_k(float* __restrict__ io, int Nrows) {
    const int lane = threadIdx.x & 63;
    const int wave = threadIdx.x >> 6;
    const int row  = blockIdx.x * 4 + wave;
    if (row >= Nrows) return;
    float2* p = (float2*)(io + (size_t)row * D);
    const float2 v = p[lane];

    float m = fmaxf(v.x, v.y);
#pragma unroll
    for (int o = 32; o; o >>= 1) m = fmaxf(m, __shfl_xor(m, o, 64));

    float e = __expf(v.x - m) + __expf(v.y - m);
#pragma unroll
    for (int o = 32; o; o >>= 1) e += __shfl_xor(e, o, 64);

    const float ls = __logf(e) + m;
    p[lane] = make_float2(v.x - ls, v.y - ls);
}

// ---------------------------------------------------------------------------
// Launch. Input order = setup_inputs() dict order:
//   0:x 1:src0 2:dst0 3:W_l0 4:W_r0 5:src1 6:dst1 7:W_l1 8:W_r1
//   9:src2 10:dst2 11:W_l2 12:W_r2
// dst_i is repeat(arange(Nt), F) with deg == F exactly -> not needed.
// ---------------------------------------------------------------------------
extern "C" void kernel_launch(void* const* d_in, const int* in_sizes, int n_in,
                              void* d_out, int out_size, void* d_ws, size_t ws_size,
                              hipStream_t stream) {
    const float* x   = (const float*)d_in[0];
    const int*   src0 = (const int*)d_in[1];
    const float* Wl0 = (const float*)d_in[3];
    const float* Wr0 = (const float*)d_in[4];
    const int*   src1 = (const int*)d_in[5];
    const float* Wl1 = (const float*)d_in[7];
    const float* Wr1 = (const float*)d_in[8];
    const int*   src2 = (const int*)d_in[9];
    const float* Wl2 = (const float*)d_in[11];
    const float* Wr2 = (const float*)d_in[12];

    float* ws  = (float*)d_ws;
    float* WT0 = ws;                         // 32768 floats
    float* WT1 = ws + 32768;
    float* WT2 = ws + 65536;
    float* h0  = ws + 98304;                 // 67584*128
    float* h1  = h0 + 67584 * 128;           // 6144*128
    float* outF = (float*)d_out;             // 1024*128

    build_wt_all<<<384, 256, 0, stream>>>(Wl0, Wr0, Wl1, Wr1, Wl2, Wr2, WT0);

    sage_layer<15><<<67584 / 32, 256, 0, stream>>>(x,  src0, WT0, h0,  1);
    sage_layer<10><<<6144  / 32, 256, 0, stream>>>(h0, src1, WT1, h1,  1);
    sage_layer<5> <<<1024  / 32, 256, 0, stream>>>(h1, src2, WT2, outF, 0);

    log_softmax_k<<<1024 / 4, 256, 0, stream>>>(outF, 1024);
}

// Round 2
// 855.239 us; speedup vs baseline: 1.0609x; 1.0609x over previous
//
#include <hip/hip_runtime.h>

#define D 128

// ---------------------------------------------------------------------------
// Build transposed+concatenated weights for one layer:
//   WT[k*128 + d] = (k < 128) ? Wl[d*128 + k] : Wr[d*128 + (k-128)]
// so that out[t][d] = sum_k A[t][k] * WT[k][d] with A = [mean | x_self].
// All 3 layers in one launch: blocks 0-127 -> layer0, 128-255 -> layer1, ...
// ---------------------------------------------------------------------------
__global__ void build_wt_all(const float* __restrict__ Wl0, const float* __restrict__ Wr0,
                             const float* __restrict__ Wl1, const float* __restrict__ Wr1,
                             const float* __restrict__ Wl2, const float* __restrict__ Wr2,
                             float* __restrict__ WT /* [3][256][128] */) {
    const int layer = blockIdx.x >> 7;
    const int i = (blockIdx.x & 127) * 256 + threadIdx.x;   // [0, 32768)
    const float* Wl = (layer == 0) ? Wl0 : (layer == 1) ? Wl1 : Wl2;
    const float* Wr = (layer == 0) ? Wr0 : (layer == 1) ? Wr1 : Wr2;
    const int k = i >> 7;        // 0..255
    const int d = i & 127;       // 0..127
    const float v = (k < D) ? Wl[d * D + k] : Wr[d * D + (k - D)];
    WT[layer * 2 * D * D + i] = v;
}

// ---------------------------------------------------------------------------
// Fused SAGE layer: for M=32 targets per block,
//   Phase 1: mean over F gathered neighbor rows + self row -> LDS A[32][256]
//   Phase 2: out = A @ WT with a 4x4 register tile per thread:
//     thread (rg = tid>>5, cg = tid&31) owns rows 4rg..4rg+3, cols 4cg..4cg+3.
//     Per k-quad: 4 ds_read_b128 (A) + 4 float4 WT loads + 64 FMAs.
//     (Previous 1x16 tiling issued 16 ds_read_b128 per k-quad -> LDS-pipe bound.)
// ---------------------------------------------------------------------------
template <int F>
__global__ __launch_bounds__(256, 4) void sage_layer(
        const float* __restrict__ x,    // [Ns, 128] source features
        const int*   __restrict__ src,  // [Nt * F]
        const float* __restrict__ WT,   // [256, 128]
        float*       __restrict__ out,  // [Nt, 128]
        int doRelu) {
    constexpr int M = 32;               // targets per block
    __shared__ float A[M][2 * D];       // 32 KB: [mean | x_self]

    const int tid  = threadIdx.x;
    const int lane = tid & 63;
    const int wave = tid >> 6;
    const int t0   = blockIdx.x * M;

    // ---- Phase 1: gather + mean (float2/lane => one full 512B row per instr)
    const float2* __restrict__ x2 = (const float2*)x;
    const float inv = 1.0f / (float)F;
    for (int mi = wave; mi < M; mi += 4) {
        const int t = t0 + mi;
        const int base = t * F;
        float2 acc = make_float2(0.f, 0.f);
#pragma unroll
        for (int j = 0; j < F; ++j) {
            const int s = src[base + j];                    // wave-uniform
            const float2 v = x2[(size_t)s * 64 + lane];     // coalesced 512B
            acc.x += v.x;
            acc.y += v.y;
        }
        const float2 xt = x2[(size_t)t * 64 + lane];        // self row
        A[mi][2 * lane]         = acc.x * inv;
        A[mi][2 * lane + 1]     = acc.y * inv;
        A[mi][D + 2 * lane]     = xt.x;
        A[mi][D + 2 * lane + 1] = xt.y;
    }
    __syncthreads();

    // ---- Phase 2: 4x4 register tile per thread
    const int cg = tid & 31;            // cols 4cg .. 4cg+3
    const int rg = tid >> 5;            // rows 4rg .. 4rg+3
    const float4* __restrict__ WT4 = (const float4*)WT;

    float4 acc0 = make_float4(0.f, 0.f, 0.f, 0.f);
    float4 acc1 = acc0, acc2 = acc0, acc3 = acc0;

#pragma unroll 4
    for (int k = 0; k < 2 * D; k += 4) {
        const float4 w0 = WT4[(k + 0) * 32 + cg];   // WT[k+0][4cg..4cg+3]
        const float4 w1 = WT4[(k + 1) * 32 + cg];
        const float4 w2 = WT4[(k + 2) * 32 + cg];
        const float4 w3 = WT4[(k + 3) * 32 + cg];
#pragma unroll
        for (int rr = 0; rr < 4; ++rr) {
            const float4 a = *(const float4*)&A[4 * rg + rr][k];  // 1 b128 / row / k-quad
            float4& c = (rr == 0) ? acc0 : (rr == 1) ? acc1 : (rr == 2) ? acc2 : acc3;
            c.x = fmaf(a.x, w0.x, c.x); c.y = fmaf(a.x, w0.y, c.y);
            c.z = fmaf(a.x, w0.z, c.z); c.w = fmaf(a.x, w0.w, c.w);
            c.x = fmaf(a.y, w1.x, c.x); c.y = fmaf(a.y, w1.y, c.y);
            c.z = fmaf(a.y, w1.z, c.z); c.w = fmaf(a.y, w1.w, c.w);
            c.x = fmaf(a.z, w2.x, c.x); c.y = fmaf(a.z, w2.y, c.y);
            c.z = fmaf(a.z, w2.z, c.z); c.w = fmaf(a.z, w2.w, c.w);
            c.x = fmaf(a.w, w3.x, c.x); c.y = fmaf(a.w, w3.y, c.y);
            c.z = fmaf(a.w, w3.z, c.z); c.w = fmaf(a.w, w3.w, c.w);
        }
    }

    float4* __restrict__ out4 = (float4*)out;
#pragma unroll
    for (int rr = 0; rr < 4; ++rr) {
        const int row = t0 + 4 * rg + rr;
        float4 v = (rr == 0) ? acc0 : (rr == 1) ? acc1 : (rr == 2) ? acc2 : acc3;
        if (doRelu) {
            v.x = fmaxf(v.x, 0.f); v.y = fmaxf(v.y, 0.f);
            v.z = fmaxf(v.z, 0.f); v.w = fmaxf(v.w, 0.f);
        }
        out4[(size_t)row * 32 + cg] = v;    // coalesced float4 stores
    }
}

// ---------------------------------------------------------------------------
// In-place log_softmax over rows of [Nrows, 128]; one wave per row.
// ---------------------------------------------------------------------------
__global__ void log_softmax_k(float* __restrict__ io, int Nrows) {
    const int lane = threadIdx.x & 63;
    const int wave = threadIdx.x >> 6;
    const int row  = blockIdx.x * 4 + wave;
    if (row >= Nrows) return;
    float2* p = (float2*)(io + (size_t)row * D);
    const float2 v = p[lane];

    float m = fmaxf(v.x, v.y);
#pragma unroll
    for (int o = 32; o; o >>= 1) m = fmaxf(m, __shfl_xor(m, o, 64));

    float e = __expf(v.x - m) + __expf(v.y - m);
#pragma unroll
    for (int o = 32; o; o >>= 1) e += __shfl_xor(e, o, 64);

    const float ls = __logf(e) + m;
    p[lane] = make_float2(v.x - ls, v.y - ls);
}

// ---------------------------------------------------------------------------
// Launch. Input order = setup_inputs() dict order:
//   0:x 1:src0 2:dst0 3:W_l0 4:W_r0 5:src1 6:dst1 7:W_l1 8:W_r1
//   9:src2 10:dst2 11:W_l2 12:W_r2
// dst_i is repeat(arange(Nt), F) with deg == F exactly -> not needed.
// ---------------------------------------------------------------------------
extern "C" void kernel_launch(void* const* d_in, const int* in_sizes, int n_in,
                              void* d_out, int out_size, void* d_ws, size_t ws_size,
                              hipStream_t stream) {
    const float* x   = (const float*)d_in[0];
    const int*   src0 = (const int*)d_in[1];
    const float* Wl0 = (const float*)d_in[3];
    const float* Wr0 = (const float*)d_in[4];
    const int*   src1 = (const int*)d_in[5];
    const float* Wl1 = (const float*)d_in[7];
    const float* Wr1 = (const float*)d_in[8];
    const int*   src2 = (const int*)d_in[9];
    const float* Wl2 = (const float*)d_in[11];
    const float* Wr2 = (const float*)d_in[12];

    float* ws  = (float*)d_ws;
    float* WT0 = ws;                         // 32768 floats
    float* WT1 = ws + 32768;
    float* WT2 = ws + 65536;
    float* h0  = ws + 98304;                 // 67584*128
    float* h1  = h0 + 67584 * 128;           // 6144*128
    float* outF = (float*)d_out;             // 1024*128

    build_wt_all<<<384, 256, 0, stream>>>(Wl0, Wr0, Wl1, Wr1, Wl2, Wr2, WT0);

    sage_layer<15><<<67584 / 32, 256, 0, stream>>>(x,  src0, WT0, h0,  1);
    sage_layer<10><<<6144  / 32, 256, 0, stream>>>(h0, src1, WT1, h1,  1);
    sage_layer<5> <<<1024  / 32, 256, 0, stream>>>(h1, src2, WT2, outF, 0);

    log_softmax_k<<<1024 / 4, 256, 0, stream>>>(outF, 1024);
}

// Round 3
// 777.341 us; speedup vs baseline: 1.1673x; 1.1002x over previous
//
#include <hip/hip_runtime.h>
#include <stdint.h>

#define D 128

typedef __attribute__((ext_vector_type(8))) short frag8;   // 8 bf16 (4 VGPRs)
typedef __attribute__((ext_vector_type(4))) float fragc;   // 4 fp32 acc

__device__ __forceinline__ short f2bf(float f) {           // RNE fp32->bf16
    uint32_t u = __float_as_uint(f);
    u += 0x7fffu + ((u >> 16) & 1u);
    return (short)(u >> 16);
}
__device__ __forceinline__ float bf2f(unsigned short h) {
    return __uint_as_float(((uint32_t)h) << 16);
}

// ---------------------------------------------------------------------------
// WTt bf16 [3][128][256]: row d = [Wl[d][0..127] | Wr[d][0..127]]  (B^T layout
// so a B-fragment's 8 k-elements are contiguous).  out[t][d] = sum_k A[t][k]*WTt[d][k].
// ---------------------------------------------------------------------------
__global__ void build_wtt(const float* __restrict__ Wl0, const float* __restrict__ Wr0,
                          const float* __restrict__ Wl1, const float* __restrict__ Wr1,
                          const float* __restrict__ Wl2, const float* __restrict__ Wr2,
                          short* __restrict__ WTt) {
    const int layer = blockIdx.x >> 7;
    const int i = (blockIdx.x & 127) * 256 + threadIdx.x;   // [0, 32768)
    const float* Wl = (layer == 0) ? Wl0 : (layer == 1) ? Wl1 : Wl2;
    const float* Wr = (layer == 0) ? Wr0 : (layer == 1) ? Wr1 : Wr2;
    const int d = i >> 8;        // 0..127
    const int k = i & 255;       // 0..255
    const float v = (k < D) ? Wl[d * D + k] : Wr[d * D + (k - D)];
    WTt[layer * 32768 + i] = f2bf(v);
}

// ---------------------------------------------------------------------------
// Fused SAGE layer, M=64 targets/block, MFMA phase 2.
//  Phase 1: gather+mean (fp32 accum) -> LDS A bf16 [64][264] = [mean | self]
//           row stride 264 bf16 = 528 B -> 2-way bank alias only (free).
//  Phase 2: wave w computes rows 16w..16w+15 x all 128 cols:
//           8 A-frags hoisted (ds_read_b128), 8 ksteps x 8 coltiles MFMA
//           16x16x32_bf16, B-frags streamed from L1-resident WTt (64 KB).
//  Epilogue: ReLU+bf16 store (layers 0,1) or fused log_softmax fp32 (layer 2).
// MFMA layouts (measured, m89/m91/m120): A: m=lane&15, k=(lane>>4)*8+j;
// B: n=lane&15, k=(lane>>4)*8+j; C/D: col=lane&15, row=(lane>>4)*4+reg.
// ---------------------------------------------------------------------------
template <int F, typename TIN, typename TOUT, bool RELU, bool SOFTMAX>
__global__ __launch_bounds__(256, 4) void sage_mfma(
        const TIN* __restrict__ x,     // [Ns][128] fp32 or bf16
        const int* __restrict__ src,   // [Nt*F]
        const short* __restrict__ WTt, // [128][256] bf16
        TOUT* __restrict__ out) {      // [Nt][128] bf16 or fp32
    constexpr int M = 64;
    constexpr int AS = 264;                 // padded A row stride (bf16 elems)
    __shared__ short A[M * AS];             // 33792 B

    const int tid  = threadIdx.x;
    const int lane = tid & 63;
    const int wave = tid >> 6;
    const int t0   = blockIdx.x * M;

    // ---- Phase 1: gather + mean; one full row per wave-instr (coalesced)
    const float inv = 1.0f / (float)F;
    for (int mi = wave; mi < M; mi += 4) {
        const int t = t0 + mi;
        const long base = (long)t * F;
        float ax = 0.f, ay = 0.f;
#pragma unroll
        for (int j = 0; j < F; ++j) {
            const int s = src[base + j];
            if constexpr (sizeof(TIN) == 4) {
                const float2 v = ((const float2*)x)[(size_t)s * 64 + lane];
                ax += v.x; ay += v.y;
            } else {
                const ushort2 u = ((const ushort2*)x)[(size_t)s * 64 + lane];
                ax += bf2f(u.x); ay += bf2f(u.y);
            }
        }
        short sx, sy;
        if constexpr (sizeof(TIN) == 4) {
            const float2 v = ((const float2*)x)[(size_t)t * 64 + lane];
            sx = f2bf(v.x); sy = f2bf(v.y);
        } else {
            const ushort2 u = ((const ushort2*)x)[(size_t)t * 64 + lane];
            sx = (short)u.x; sy = (short)u.y;
        }
        *(short2*)&A[mi * AS + 2 * lane]     = make_short2(f2bf(ax * inv), f2bf(ay * inv));
        *(short2*)&A[mi * AS + D + 2 * lane] = make_short2(sx, sy);
    }
    __syncthreads();

    // ---- Phase 2: MFMA
    const int m    = lane & 15;
    const int quad = lane >> 4;
    const int r0   = wave * 16;

    frag8 af[8];
    const short* arow = &A[(r0 + m) * AS + quad * 8];
#pragma unroll
    for (int ks = 0; ks < 8; ++ks)
        af[ks] = *(const frag8*)(arow + ks * 32);

    fragc acc[8];
#pragma unroll
    for (int ct = 0; ct < 8; ++ct) acc[ct] = (fragc)0.f;

#pragma unroll
    for (int ks = 0; ks < 8; ++ks) {
        const short* bbase = WTt + m * 256 + ks * 32 + quad * 8;
#pragma unroll
        for (int ct = 0; ct < 8; ++ct) {      // independent accs back-to-back
            const frag8 bf = *(const frag8*)(bbase + ct * 16 * 256);
            acc[ct] = __builtin_amdgcn_mfma_f32_16x16x32_bf16(af[ks], bf, acc[ct], 0, 0, 0);
        }
    }

    // ---- Epilogue
    if constexpr (!SOFTMAX) {
#pragma unroll
        for (int ct = 0; ct < 8; ++ct) {
#pragma unroll
            for (int reg = 0; reg < 4; ++reg) {
                float v = acc[ct][reg];
                if constexpr (RELU) v = fmaxf(v, 0.f);
                const int row = t0 + r0 + quad * 4 + reg;
                const int col = ct * 16 + m;
                if constexpr (sizeof(TOUT) == 2)
                    out[(size_t)row * D + col] = (TOUT)f2bf(v);
                else
                    out[(size_t)row * D + col] = (TOUT)v;
            }
        }
    } else {
        // rows quad*4+reg live across the quad's 16 lanes x 8 coltile regs
#pragma unroll
        for (int reg = 0; reg < 4; ++reg) {
            float mx = -3.4e38f;
#pragma unroll
            for (int ct = 0; ct < 8; ++ct) mx = fmaxf(mx, acc[ct][reg]);
#pragma unroll
            for (int off = 1; off < 16; off <<= 1) mx = fmaxf(mx, __shfl_xor(mx, off, 64));
            float s = 0.f;
#pragma unroll
            for (int ct = 0; ct < 8; ++ct) s += __expf(acc[ct][reg] - mx);
#pragma unroll
            for (int off = 1; off < 16; off <<= 1) s += __shfl_xor(s, off, 64);
            const float ls = __logf(s) + mx;
            const int row = t0 + r0 + quad * 4 + reg;
#pragma unroll
            for (int ct = 0; ct < 8; ++ct)
                ((float*)out)[(size_t)row * D + ct * 16 + m] = acc[ct][reg] - ls;
        }
    }
}

// ---------------------------------------------------------------------------
// Inputs (setup_inputs order): 0:x 1:src0 2:dst0 3:Wl0 4:Wr0 5:src1 6:dst1
// 7:Wl1 8:Wr1 9:src2 10:dst2 11:Wl2 12:Wr2.  dst_i == repeat(arange, F), deg==F.
// ---------------------------------------------------------------------------
extern "C" void kernel_launch(void* const* d_in, const int* in_sizes, int n_in,
                              void* d_out, int out_size, void* d_ws, size_t ws_size,
                              hipStream_t stream) {
    const float* x    = (const float*)d_in[0];
    const int*   src0 = (const int*)d_in[1];
    const float* Wl0  = (const float*)d_in[3];
    const float* Wr0  = (const float*)d_in[4];
    const int*   src1 = (const int*)d_in[5];
    const float* Wl1  = (const float*)d_in[7];
    const float* Wr1  = (const float*)d_in[8];
    const int*   src2 = (const int*)d_in[9];
    const float* Wl2  = (const float*)d_in[11];
    const float* Wr2  = (const float*)d_in[12];

    short* WTt = (short*)d_ws;               // 3*32768 bf16
    short* h0  = WTt + 3 * 32768;            // 67584*128 bf16
    short* h1  = h0 + 67584 * 128;           // 6144*128 bf16
    float* outF = (float*)d_out;             // 1024*128 fp32

    build_wtt<<<384, 256, 0, stream>>>(Wl0, Wr0, Wl1, Wr1, Wl2, Wr2, WTt);

    sage_mfma<15, float, short, true,  false><<<67584 / 64, 256, 0, stream>>>(x,  src0, WTt,          h0);
    sage_mfma<10, short, short, true,  false><<<6144  / 64, 256, 0, stream>>>(h0, src1, WTt + 32768,  h1);
    sage_mfma<5,  short, float, false, true ><<<1024  / 64, 256, 0, stream>>>(h1, src2, WTt + 65536,  outF);
}